// Round 7
// baseline (279.745 us; speedup 1.0000x reference)
//
#include <hip/hip_runtime.h>
#include <hip/hip_fp16.h>

// ---------------------------------------------------------------------------
// GAT policy module: 2x GAT layer (head-mean) + mean-pool + 2 MLP heads.
// Round 6: aggregate-then-transform dataflow flip.
//   scores:  a_src[n,h] = x[n] . (W_h @ att_s_h)   (h1pre never built)
//   agg:     agg[n,h,:] = sum_src alpha * x[src]   (gathers the SMALL table:
//            x_h 5 MB vs h1pre 10 MB -> near-L2-resident, half the bytes)
//   gemm:    h1 = relu(1/H * agg[N,H*K] @ Wstack[H*K,C] + b)   (MFMA fp16)
// Layer 2 identical with h1 (2.5 MB, fully L2-resident gather).
// ---------------------------------------------------------------------------

#define G_GRAPHS 64

using half8   = __attribute__((ext_vector_type(8))) _Float16;
using half4v  = __attribute__((ext_vector_type(4))) _Float16;
using floatx4 = __attribute__((ext_vector_type(4))) float;

__device__ inline float lrelu(float v) { return (v > 0.f) ? v : 0.2f * v; }

// ---------------------------------------------------------------------------
// Merged prep: cast x -> fp16; build w_att1/w_att2 (W_h @ att vectors);
// build stacked weights Wstack1 [512,64], Wstack2 [128,32] in fp16.
// Grid = castBlocks + 3 + 8.
// ---------------------------------------------------------------------------
__global__ __launch_bounds__(256) void prep_kernel(
        const float* __restrict__ x, const float* __restrict__ W1,
        const float* __restrict__ as1, const float* __restrict__ ad1,
        const float* __restrict__ W2, const float* __restrict__ as2,
        const float* __restrict__ ad2,
        _Float16* __restrict__ x_h, float* __restrict__ w_att1,
        float* __restrict__ w_att2, _Float16* __restrict__ Wstack1,
        _Float16* __restrict__ Wstack2, int n4x)
{
    const int bid = blockIdx.x;
    const int castBlocks = (n4x + 255) / 256;
    if (bid < castBlocks) {
        int i = bid * 256 + threadIdx.x;
        if (i < n4x) {
            float4 v = reinterpret_cast<const float4*>(x)[i];
            half4v h = { (_Float16)v.x, (_Float16)v.y, (_Float16)v.z, (_Float16)v.w };
            reinterpret_cast<half4v*>(x_h)[i] = h;
        }
        return;
    }
    const int t = bid - castBlocks;
    if (t == 0) {
        // w_att1: [s|d][h=4][k=128];  w_s[h][k] = sum_c W1[k,h*64+c]*as1[h,c]
        for (int idx = threadIdx.x; idx < 512; idx += 256) {
            int h = idx >> 7, k = idx & 127;
            float ss = 0.f, sd = 0.f;
            for (int c = 0; c < 64; c++) {
                float wv = W1[k * 256 + h * 64 + c];
                ss += wv * as1[h * 64 + c];
                sd += wv * ad1[h * 64 + c];
            }
            w_att1[h * 128 + k] = ss;
            w_att1[512 + h * 128 + k] = sd;
        }
    } else if (t == 1) {
        // w_att2: [s|d][h=2][k=64]
        for (int idx = threadIdx.x; idx < 128; idx += 256) {
            int h = idx >> 6, k = idx & 63;
            float ss = 0.f, sd = 0.f;
            for (int c = 0; c < 32; c++) {
                float wv = W2[k * 64 + h * 32 + c];
                ss += wv * as2[h * 32 + c];
                sd += wv * ad2[h * 32 + c];
            }
            w_att2[h * 64 + k] = ss;
            w_att2[128 + h * 64 + k] = sd;
        }
    } else if (t == 2) {
        // Wstack2[h*64+k][c] = W2[k][h*32+c], 128x32
        for (int e = threadIdx.x; e < 4096; e += 256) {
            int row = e >> 5, c = e & 31;
            int h = row >> 6, k = row & 63;
            Wstack2[e] = (_Float16)W2[k * 64 + h * 32 + c];
        }
    } else {
        // Wstack1[h*128+k][c] = W1[k][h*64+c], 512x64 over 8 blocks
        int wb = t - 3;
        for (int e = wb * 4096 + threadIdx.x; e < (wb + 1) * 4096; e += 256) {
            int row = e >> 6, c = e & 63;
            int h = row >> 7, k = row & 127;
            Wstack1[e] = (_Float16)W1[k * 256 + h * 64 + c];
        }
    }
}

// ---------------------------------------------------------------------------
// Scores: a_s[n,h] = X[n,:] . w_att[s-block h], a_d likewise. Thread/(n,h).
// w_att layout: first H*K floats = s vectors, next H*K = d vectors.
// ---------------------------------------------------------------------------
template<int H, int K>
__global__ __launch_bounds__(256) void score_kernel(
        const _Float16* __restrict__ X, const float* __restrict__ w_att,
        float* __restrict__ a_s, float* __restrict__ a_d, int N)
{
    int idx = blockIdx.x * 256 + threadIdx.x;
    if (idx >= N * H) return;
    int n = idx / H, h = idx % H;
    const __half2* xp = reinterpret_cast<const __half2*>(X + (size_t)n * K);
    const float* ws = w_att + h * K;
    const float* wd = w_att + H * K + h * K;
    float ss = 0.f, sd = 0.f;
    #pragma unroll 8
    for (int k2 = 0; k2 < K / 2; k2++) {
        float2 f = __half22float2(xp[k2]);
        ss += f.x * ws[2 * k2] + f.y * ws[2 * k2 + 1];
        sd += f.x * wd[2 * k2] + f.y * wd[2 * k2 + 1];
    }
    a_s[idx] = ss;
    a_d[idx] = sd;
}

// ---------------------------------------------------------------------------
// CSR build: degree count -> exclusive scan -> bucket fill.
// ---------------------------------------------------------------------------
__global__ __launch_bounds__(256) void csr_count(
        const int* __restrict__ ei, int* __restrict__ deg, int E0, int Etot)
{
    int idx = blockIdx.x * 256 + threadIdx.x;
    if (idx >= Etot) return;
    int dst = (idx < E0) ? ei[E0 + idx] : (idx - E0);
    atomicAdd(&deg[dst], 1);
}

__global__ __launch_bounds__(1024) void csr_scan(
        const int* __restrict__ deg, int* __restrict__ rowptr,
        int* __restrict__ cursor, int N)
{
    const int tid = threadIdx.x;
    const int items = (N + 1023) >> 10;
    const int b = tid * items;
    int sum = 0;
    for (int k = 0; k < items; k++) {
        int i = b + k;
        sum += (i < N) ? deg[i] : 0;
    }
    __shared__ int smem[1024];
    smem[tid] = sum;
    __syncthreads();
    for (int off = 1; off < 1024; off <<= 1) {
        int t = (tid >= off) ? smem[tid - off] : 0;
        __syncthreads();
        smem[tid] += t;
        __syncthreads();
    }
    int excl = smem[tid] - sum;
    for (int k = 0; k < items; k++) {
        int i = b + k;
        if (i < N) {
            rowptr[i] = excl; cursor[i] = excl;
            excl += deg[i];
        }
    }
    if (tid == 1023) rowptr[N] = excl;
}

__global__ __launch_bounds__(256) void csr_fill(
        const int* __restrict__ ei, int* __restrict__ cursor,
        int* __restrict__ col, int E0, int Etot)
{
    int idx = blockIdx.x * 256 + threadIdx.x;
    if (idx >= Etot) return;
    int src = (idx < E0) ? ei[idx]      : (idx - E0);
    int dst = (idx < E0) ? ei[E0 + idx] : (idx - E0);
    int pos = atomicAdd(&cursor[dst], 1);
    col[pos] = src;
}

// ---------------------------------------------------------------------------
// Layer-1 aggregation: one wave per dst node (H=4, Kx=128).
// agg[d, h*128 + k] = (1/l_h) sum_src p_h * x[src,k]    (fp16 out)
// Lane holds channels 2*lane, 2*lane+1; acc[4][2] fp32 in regs.
// ---------------------------------------------------------------------------
__global__ __launch_bounds__(256) void gat_agg1(
        const int* __restrict__ rowptr, const int* __restrict__ colidx,
        const _Float16* __restrict__ x_h, const float* __restrict__ a_s,
        const float* __restrict__ a_d, _Float16* __restrict__ agg, int N)
{
    const int wid  = threadIdx.x >> 6;
    const int lane = threadIdx.x & 63;
    const int d = blockIdx.x * 4 + wid;
    __shared__ float4 p_sh[4][64];
    if (d >= N) return;
    const int lo = rowptr[d], hi = rowptr[d + 1];
    const int deg = hi - lo;
    const float4 adp = *reinterpret_cast<const float4*>(&a_d[d * 4]);
    const int c2 = lane * 2;

    float l[4] = {};
    float acc[4][2] = {};

    if (deg <= 64) {
        int s = 0;
        float e[4];
        const bool valid = lane < deg;
        if (valid) {
            s = colidx[lo + lane];
            float4 av = *reinterpret_cast<const float4*>(&a_s[s * 4]);
            e[0] = lrelu(av.x + adp.x); e[1] = lrelu(av.y + adp.y);
            e[2] = lrelu(av.z + adp.z); e[3] = lrelu(av.w + adp.w);
        } else {
            e[0] = e[1] = e[2] = e[3] = -3.0e38f;
        }
        float m[4] = {e[0], e[1], e[2], e[3]};
        #pragma unroll
        for (int off = 1; off < 64; off <<= 1)
            #pragma unroll
            for (int h = 0; h < 4; h++)
                m[h] = fmaxf(m[h], __shfl_xor(m[h], off));
        float4 pv = {0.f, 0.f, 0.f, 0.f};
        if (valid) {
            pv.x = __expf(e[0] - m[0]); pv.y = __expf(e[1] - m[1]);
            pv.z = __expf(e[2] - m[2]); pv.w = __expf(e[3] - m[3]);
        }
        p_sh[wid][lane] = pv;
        l[0] = pv.x; l[1] = pv.y; l[2] = pv.z; l[3] = pv.w;
        #pragma unroll
        for (int off = 1; off < 64; off <<= 1)
            #pragma unroll
            for (int h = 0; h < 4; h++)
                l[h] += __shfl_xor(l[h], off);

        // ---- gather x rows, 4 edges in flight ----
        float acc1[4][2] = {}, acc2[4][2] = {}, acc3[4][2] = {};
        int j = 0;
        for (; j + 4 <= deg; j += 4) {
            int s0 = __shfl(s, j + 0), s1 = __shfl(s, j + 1);
            int s2 = __shfl(s, j + 2), s3 = __shfl(s, j + 3);
            float4 p0 = p_sh[wid][j + 0], p1 = p_sh[wid][j + 1];
            float4 p2 = p_sh[wid][j + 2], p3 = p_sh[wid][j + 3];
            float2 f0 = __half22float2(*reinterpret_cast<const __half2*>(&x_h[(size_t)s0 * 128 + c2]));
            float2 f1 = __half22float2(*reinterpret_cast<const __half2*>(&x_h[(size_t)s1 * 128 + c2]));
            float2 f2 = __half22float2(*reinterpret_cast<const __half2*>(&x_h[(size_t)s2 * 128 + c2]));
            float2 f3 = __half22float2(*reinterpret_cast<const __half2*>(&x_h[(size_t)s3 * 128 + c2]));
            acc [0][0] += p0.x * f0.x; acc [0][1] += p0.x * f0.y;
            acc [1][0] += p0.y * f0.x; acc [1][1] += p0.y * f0.y;
            acc [2][0] += p0.z * f0.x; acc [2][1] += p0.z * f0.y;
            acc [3][0] += p0.w * f0.x; acc [3][1] += p0.w * f0.y;
            acc1[0][0] += p1.x * f1.x; acc1[0][1] += p1.x * f1.y;
            acc1[1][0] += p1.y * f1.x; acc1[1][1] += p1.y * f1.y;
            acc1[2][0] += p1.z * f1.x; acc1[2][1] += p1.z * f1.y;
            acc1[3][0] += p1.w * f1.x; acc1[3][1] += p1.w * f1.y;
            acc2[0][0] += p2.x * f2.x; acc2[0][1] += p2.x * f2.y;
            acc2[1][0] += p2.y * f2.x; acc2[1][1] += p2.y * f2.y;
            acc2[2][0] += p2.z * f2.x; acc2[2][1] += p2.z * f2.y;
            acc2[3][0] += p2.w * f2.x; acc2[3][1] += p2.w * f2.y;
            acc3[0][0] += p3.x * f3.x; acc3[0][1] += p3.x * f3.y;
            acc3[1][0] += p3.y * f3.x; acc3[1][1] += p3.y * f3.y;
            acc3[2][0] += p3.z * f3.x; acc3[2][1] += p3.z * f3.y;
            acc3[3][0] += p3.w * f3.x; acc3[3][1] += p3.w * f3.y;
        }
        for (; j < deg; j++) {
            int s_j = __shfl(s, j);
            float4 pj = p_sh[wid][j];
            float2 f = __half22float2(*reinterpret_cast<const __half2*>(&x_h[(size_t)s_j * 128 + c2]));
            acc[0][0] += pj.x * f.x; acc[0][1] += pj.x * f.y;
            acc[1][0] += pj.y * f.x; acc[1][1] += pj.y * f.y;
            acc[2][0] += pj.z * f.x; acc[2][1] += pj.z * f.y;
            acc[3][0] += pj.w * f.x; acc[3][1] += pj.w * f.y;
        }
        #pragma unroll
        for (int h = 0; h < 4; h++) {
            acc[h][0] = (acc[h][0] + acc1[h][0]) + (acc2[h][0] + acc3[h][0]);
            acc[h][1] = (acc[h][1] + acc1[h][1]) + (acc2[h][1] + acc3[h][1]);
        }
    } else {
        // general path (deg > 64, rare)
        float m[4] = {-3.0e38f, -3.0e38f, -3.0e38f, -3.0e38f};
        for (int i = lo + lane; i < hi; i += 64) {
            int s = colidx[i];
            float4 av = *reinterpret_cast<const float4*>(&a_s[s * 4]);
            m[0] = fmaxf(m[0], lrelu(av.x + adp.x));
            m[1] = fmaxf(m[1], lrelu(av.y + adp.y));
            m[2] = fmaxf(m[2], lrelu(av.z + adp.z));
            m[3] = fmaxf(m[3], lrelu(av.w + adp.w));
        }
        #pragma unroll
        for (int off = 1; off < 64; off <<= 1)
            #pragma unroll
            for (int h = 0; h < 4; h++)
                m[h] = fmaxf(m[h], __shfl_xor(m[h], off));

        for (int base = lo; base < hi; base += 64) {
            int i = base + lane;
            int s = 0;
            float4 pv = {0.f, 0.f, 0.f, 0.f};
            if (i < hi) {
                s = colidx[i];
                float4 av = *reinterpret_cast<const float4*>(&a_s[s * 4]);
                pv.x = __expf(lrelu(av.x + adp.x) - m[0]);
                pv.y = __expf(lrelu(av.y + adp.y) - m[1]);
                pv.z = __expf(lrelu(av.z + adp.z) - m[2]);
                pv.w = __expf(lrelu(av.w + adp.w) - m[3]);
                l[0] += pv.x; l[1] += pv.y; l[2] += pv.z; l[3] += pv.w;
            }
            p_sh[wid][lane] = pv;
            int cnt = min(64, hi - base);
            for (int j = 0; j < cnt; j++) {
                int s_j = __shfl(s, j);
                float4 pj = p_sh[wid][j];
                float2 f = __half22float2(*reinterpret_cast<const __half2*>(&x_h[(size_t)s_j * 128 + c2]));
                acc[0][0] += pj.x * f.x; acc[0][1] += pj.x * f.y;
                acc[1][0] += pj.y * f.x; acc[1][1] += pj.y * f.y;
                acc[2][0] += pj.z * f.x; acc[2][1] += pj.z * f.y;
                acc[3][0] += pj.w * f.x; acc[3][1] += pj.w * f.y;
            }
        }
        #pragma unroll
        for (int off = 1; off < 64; off <<= 1)
            #pragma unroll
            for (int h = 0; h < 4; h++)
                l[h] += __shfl_xor(l[h], off);
    }

    // epilogue: normalize per head, store fp16
    #pragma unroll
    for (int h = 0; h < 4; h++) {
        float inv = 1.0f / (l[h] + 1e-16f);
        __half2 hv = __floats2half2_rn(acc[h][0] * inv, acc[h][1] * inv);
        *reinterpret_cast<__half2*>(&agg[(size_t)d * 512 + h * 128 + c2]) = hv;
    }
}

// ---------------------------------------------------------------------------
// Layer-2 aggregation: one wave per dst node (H=2, Kx=64).
// Lanes split: half = lane>>5 handles edge jj+half; ch2 = (lane&31)*2.
// agg2[d, h*64 + k] fp16.
// ---------------------------------------------------------------------------
__global__ __launch_bounds__(256) void gat_agg2(
        const int* __restrict__ rowptr, const int* __restrict__ colidx,
        const _Float16* __restrict__ h1_h, const float* __restrict__ a_s,
        const float* __restrict__ a_d, _Float16* __restrict__ agg2, int N)
{
    const int wid  = threadIdx.x >> 6;
    const int lane = threadIdx.x & 63;
    const int d = blockIdx.x * 4 + wid;
    __shared__ float2 p_sh[4][64];
    if (d >= N) return;
    const int lo = rowptr[d], hi = rowptr[d + 1];
    const int deg = hi - lo;
    const float2 adp = *reinterpret_cast<const float2*>(&a_d[d * 2]);
    const int half = lane >> 5;
    const int ch2 = (lane & 31) * 2;

    float l[2] = {};
    float acc[2][2] = {}, accB[2][2] = {};

    if (deg <= 64) {
        int s = 0;
        float e0, e1;
        const bool valid = lane < deg;
        if (valid) {
            s = colidx[lo + lane];
            float2 av = *reinterpret_cast<const float2*>(&a_s[s * 2]);
            e0 = lrelu(av.x + adp.x); e1 = lrelu(av.y + adp.y);
        } else { e0 = e1 = -3.0e38f; }
        float m0 = e0, m1 = e1;
        #pragma unroll
        for (int off = 1; off < 64; off <<= 1) {
            m0 = fmaxf(m0, __shfl_xor(m0, off));
            m1 = fmaxf(m1, __shfl_xor(m1, off));
        }
        float2 pv = {0.f, 0.f};
        if (valid) { pv.x = __expf(e0 - m0); pv.y = __expf(e1 - m1); }
        p_sh[wid][lane] = pv;
        l[0] = pv.x; l[1] = pv.y;
        #pragma unroll
        for (int off = 1; off < 64; off <<= 1) {
            l[0] += __shfl_xor(l[0], off);
            l[1] += __shfl_xor(l[1], off);
        }

        int jj = 0;
        for (; jj + 4 <= deg; jj += 4) {        // 2 edges/lane, both valid
            int ja = jj + half, jb = jj + 2 + half;
            int sa = __shfl(s, ja), sb = __shfl(s, jb);
            float2 pa = p_sh[wid][ja], pb = p_sh[wid][jb];
            float2 fa = __half22float2(*reinterpret_cast<const __half2*>(&h1_h[(size_t)sa * 64 + ch2]));
            float2 fb = __half22float2(*reinterpret_cast<const __half2*>(&h1_h[(size_t)sb * 64 + ch2]));
            acc [0][0] += pa.x * fa.x; acc [0][1] += pa.x * fa.y;
            acc [1][0] += pa.y * fa.x; acc [1][1] += pa.y * fa.y;
            accB[0][0] += pb.x * fb.x; accB[0][1] += pb.x * fb.y;
            accB[1][0] += pb.y * fb.x; accB[1][1] += pb.y * fb.y;
        }
        for (; jj < deg; jj += 2) {
            int j = jj + half;
            int jcl = min(j, deg - 1);
            int sj = __shfl(s, jcl);
            float2 pj = p_sh[wid][jcl];
            if (j >= deg) { pj.x = 0.f; pj.y = 0.f; }
            float2 f = __half22float2(*reinterpret_cast<const __half2*>(&h1_h[(size_t)sj * 64 + ch2]));
            acc[0][0] += pj.x * f.x; acc[0][1] += pj.x * f.y;
            acc[1][0] += pj.y * f.x; acc[1][1] += pj.y * f.y;
        }
    } else {
        // general path (deg > 64, rare)
        float m0 = -3.0e38f, m1 = -3.0e38f;
        for (int i = lo + lane; i < hi; i += 64) {
            int s = colidx[i];
            float2 av = *reinterpret_cast<const float2*>(&a_s[s * 2]);
            m0 = fmaxf(m0, lrelu(av.x + adp.x));
            m1 = fmaxf(m1, lrelu(av.y + adp.y));
        }
        #pragma unroll
        for (int off = 1; off < 64; off <<= 1) {
            m0 = fmaxf(m0, __shfl_xor(m0, off));
            m1 = fmaxf(m1, __shfl_xor(m1, off));
        }
        for (int base = lo; base < hi; base += 64) {
            int i = base + lane;
            int s = 0;
            float2 pv = {0.f, 0.f};
            if (i < hi) {
                s = colidx[i];
                float2 av = *reinterpret_cast<const float2*>(&a_s[s * 2]);
                pv.x = __expf(lrelu(av.x + adp.x) - m0);
                pv.y = __expf(lrelu(av.y + adp.y) - m1);
                l[0] += pv.x; l[1] += pv.y;
            }
            p_sh[wid][lane] = pv;
            int cnt = min(64, hi - base);
            for (int jj = 0; jj < cnt; jj += 2) {
                int j = jj + half;
                int jcl = min(j, cnt - 1);
                int sj = __shfl(s, jcl);
                float2 pj = p_sh[wid][jcl];
                if (j >= cnt) { pj.x = 0.f; pj.y = 0.f; }
                float2 f = __half22float2(*reinterpret_cast<const __half2*>(&h1_h[(size_t)sj * 64 + ch2]));
                acc[0][0] += pj.x * f.x; acc[0][1] += pj.x * f.y;
                acc[1][0] += pj.y * f.x; acc[1][1] += pj.y * f.y;
            }
        }
        #pragma unroll
        for (int off = 1; off < 64; off <<= 1) {
            l[0] += __shfl_xor(l[0], off);
            l[1] += __shfl_xor(l[1], off);
        }
    }

    // combine halves + epilogue
    #pragma unroll
    for (int h = 0; h < 2; h++) {
        acc[h][0] += accB[h][0]; acc[h][1] += accB[h][1];
        acc[h][0] += __shfl_xor(acc[h][0], 32);
        acc[h][1] += __shfl_xor(acc[h][1], 32);
    }
    float invh = 1.0f / (((half == 0) ? l[0] : l[1]) + 1e-16f);
    float v0 = ((half == 0) ? acc[0][0] : acc[1][0]) * invh;
    float v1 = ((half == 0) ? acc[0][1] : acc[1][1]) * invh;
    __half2 hv = __floats2half2_rn(v0, v1);
    *reinterpret_cast<__half2*>(&agg2[(size_t)d * 128 + half * 64 + ch2]) = hv;
}

// ---------------------------------------------------------------------------
// MFMA fp16 GEMM: out[M, NT*16] = relu(scale * A[M,KTOT] @ B[KTOT,NT*16] + b)
// 64-row blocks, 256 thr (4 waves x 16 rows), K chunks of 128.
// ---------------------------------------------------------------------------
template<int KTOT, int NT>
__global__ __launch_bounds__(256) void gemm_stack(
        const _Float16* __restrict__ A, const _Float16* __restrict__ B,
        _Float16* __restrict__ out, const float* __restrict__ bias,
        float scale, int M)
{
    constexpr int BK = 128;
    constexpr int NCOL = NT * 16;
    __shared__ _Float16 As[64][BK + 8];
    __shared__ _Float16 Bt[NCOL][BK + 8];

    const int tid  = threadIdx.x;
    const int row0 = blockIdx.x * 64;
    const int wid  = tid >> 6;
    const int lane = tid & 63;
    const int r    = lane & 15;
    const int quad = lane >> 4;
    const int rw0  = wid * 16;

    floatx4 acc[NT] = {};

    for (int kc = 0; kc < KTOT; kc += BK) {
        {   // stage A: 64 rows x 128 halves
            int row = tid >> 2;
            int k4  = (tid & 3) * 32;
            int gr  = row0 + row;
            #pragma unroll
            for (int i = 0; i < 4; i++) {
                half8 v = {};
                if (gr < M)
                    v = *reinterpret_cast<const half8*>(&A[(size_t)gr * KTOT + kc + k4 + i * 8]);
                *reinterpret_cast<half8*>(&As[row][k4 + i * 8]) = v;
            }
        }
        {   // stage B transposed: Bt[n][k]
            #pragma unroll
            for (int i = 0; i < (BK * NT * 4) / 256; i++) {
                int id = tid + 256 * i;
                int k  = id / (NT * 4);
                int n4 = (id % (NT * 4)) * 4;
                half4v v = *reinterpret_cast<const half4v*>(&B[(size_t)(kc + k) * NCOL + n4]);
                Bt[n4 + 0][k] = v[0]; Bt[n4 + 1][k] = v[1];
                Bt[n4 + 2][k] = v[2]; Bt[n4 + 3][k] = v[3];
            }
        }
        __syncthreads();
        #pragma unroll
        for (int s = 0; s < BK / 32; s++) {
            half8 af = *reinterpret_cast<const half8*>(&As[rw0 + r][s * 32 + quad * 8]);
            #pragma unroll
            for (int nt = 0; nt < NT; nt++) {
                half8 bf = *reinterpret_cast<const half8*>(&Bt[nt * 16 + r][s * 32 + quad * 8]);
                acc[nt] = __builtin_amdgcn_mfma_f32_16x16x32_f16(af, bf, acc[nt], 0, 0, 0);
            }
        }
        __syncthreads();
    }

    #pragma unroll
    for (int nt = 0; nt < NT; nt++) {
        float bv = bias[nt * 16 + r];
        #pragma unroll
        for (int reg = 0; reg < 4; reg++) {
            int gr = row0 + rw0 + quad * 4 + reg;
            if (gr < M) {
                float v = fmaxf(scale * acc[nt][reg] + bv, 0.f);
                out[(size_t)gr * NCOL + nt * 16 + r] = (_Float16)v;
            }
        }
    }
}

// ---------------------------------------------------------------------------
// Global mean pool (fp16 input), one block per graph (batch sorted).
// ---------------------------------------------------------------------------
__global__ __launch_bounds__(256) void pool_pergraph(
        const _Float16* __restrict__ h2, const int* __restrict__ batch,
        float* __restrict__ emb, int N)
{
    const int g = blockIdx.x;
    const int c = threadIdx.x & 31;
    const int r = threadIdx.x >> 5;

    __shared__ int bounds[2];
    if (threadIdx.x < 2) {
        int target = g + (int)threadIdx.x;
        int lo = 0, hi = N;
        while (lo < hi) {
            int mid = (lo + hi) >> 1;
            if (batch[mid] < target) lo = mid + 1; else hi = mid;
        }
        bounds[threadIdx.x] = lo;
    }
    __syncthreads();
    const int lo = bounds[0], hi = bounds[1];

    float acc = 0.f;
    for (int n = lo + r; n < hi; n += 8)
        acc += (float)h2[(size_t)n * 32 + c];

    __shared__ float red[8][32];
    red[r][c] = acc;
    __syncthreads();
    if (r == 0) {
        float s = 0.f;
        #pragma unroll
        for (int i = 0; i < 8; i++) s += red[i][c];
        emb[g * 32 + c] = s / fmaxf((float)(hi - lo), 1.0f);
    }
}

// ---------------------------------------------------------------------------
// Heads: two 32->16->1 MLPs + sigmoid. out[0:64]=halt, out[64:128]=cont.
// ---------------------------------------------------------------------------
__global__ __launch_bounds__(64) void heads_kernel(
        const float* __restrict__ embg,
        const float* __restrict__ cW1, const float* __restrict__ cb1,
        const float* __restrict__ cW2, const float* __restrict__ cb2,
        const float* __restrict__ hW1, const float* __restrict__ hb1,
        const float* __restrict__ hW2, const float* __restrict__ hb2,
        float* __restrict__ out)
{
    int g = threadIdx.x;
    if (g >= G_GRAPHS) return;
    float emb[32];
    #pragma unroll
    for (int c = 0; c < 32; c++) emb[c] = embg[g * 32 + c];

    float sc = cb2[0];
    #pragma unroll
    for (int j = 0; j < 16; j++) {
        float s = cb1[j];
        #pragma unroll
        for (int c = 0; c < 32; c++) s += emb[c] * cW1[c * 16 + j];
        sc += fmaxf(s, 0.f) * cW2[j];
    }
    float cont = 1.0f / (1.0f + __expf(-sc));

    float sh = hb2[0];
    #pragma unroll
    for (int j = 0; j < 16; j++) {
        float s = hb1[j];
        #pragma unroll
        for (int c = 0; c < 32; c++) s += emb[c] * hW1[c * 16 + j];
        sh += fmaxf(s, 0.f) * hW2[j];
    }
    float halt = 1.0f / (1.0f + __expf(-sh));

    out[g] = halt;
    out[G_GRAPHS + g] = cont;
}

// ---------------------------------------------------------------------------
extern "C" void kernel_launch(void* const* d_in, const int* in_sizes, int n_in,
                              void* d_out, int out_size, void* d_ws, size_t ws_size,
                              hipStream_t stream)
{
    const float* x   = (const float*)d_in[0];
    const int*   ei  = (const int*)  d_in[1];
    const int*   bat = (const int*)  d_in[2];
    const float* W1  = (const float*)d_in[3];
    const float* as1 = (const float*)d_in[4];
    const float* ad1 = (const float*)d_in[5];
    const float* b1  = (const float*)d_in[6];
    const float* W2  = (const float*)d_in[7];
    const float* as2 = (const float*)d_in[8];
    const float* ad2 = (const float*)d_in[9];
    const float* b2  = (const float*)d_in[10];
    const float* cW1 = (const float*)d_in[11];
    const float* cb1 = (const float*)d_in[12];
    const float* cW2 = (const float*)d_in[13];
    const float* cb2 = (const float*)d_in[14];
    const float* hW1 = (const float*)d_in[15];
    const float* hb1 = (const float*)d_in[16];
    const float* hW2 = (const float*)d_in[17];
    const float* hb2 = (const float*)d_in[18];

    const int N    = in_sizes[2];           // 20000
    const int E0   = in_sizes[1] / 2;       // 320000
    const int Etot = E0 + N;                // + self loops
    const int IN   = in_sizes[0] / N;       // 128

    // ---- workspace carve (float-granular) ----
    float* w = (float*)d_ws;
    size_t o = 0;
    _Float16* x_h     = (_Float16*)(w + o); o += (size_t)N * IN / 2;   // [N,128]
    _Float16* agg1    = (_Float16*)(w + o); o += (size_t)N * 256;      // [N,512]
    _Float16* agg2    = (_Float16*)(w + o); o += (size_t)N * 64;       // [N,128]
    _Float16* h1_h    = (_Float16*)(w + o); o += (size_t)N * 32;       // [N,64]
    _Float16* h2_h    = (_Float16*)(w + o); o += (size_t)N * 16;       // [N,32]
    _Float16* Wstack1 = (_Float16*)(w + o); o += 512 * 64 / 2;
    _Float16* Wstack2 = (_Float16*)(w + o); o += 128 * 32 / 2;
    float* w_att1 = w + o; o += 1024;       // [s|d][4][128]
    float* w_att2 = w + o; o += 256;        // [s|d][2][64]
    float* a_s1  = w + o; o += (size_t)N * 4;
    float* a_d1  = w + o; o += (size_t)N * 4;
    float* a_s2  = w + o; o += (size_t)N * 2;
    float* a_d2  = w + o; o += (size_t)N * 2;
    float* emb   = w + o; o += (size_t)G_GRAPHS * 32;
    int* rowptr  = (int*)(w + o); o += (size_t)N + 1;
    int* cursor  = (int*)(w + o); o += (size_t)N;
    int* deg     = (int*)(w + o); o += (size_t)N;
    int* colidx  = (int*)(w + o); o += (size_t)Etot;
    (void)ws_size; (void)n_in; (void)out_size;

    const dim3 blk(256);
    const int eb  = (Etot + 255) / 256;
    const int nb4 = (N + 3) / 4;
    const int mb  = (N + 63) / 64;
    const int n4x = N * IN / 4;
    const int castBlocks = (n4x + 255) / 256;

    // ---- prep (casts, w_att, Wstacks) + CSR build ----
    hipMemsetAsync(deg, 0, (size_t)N * sizeof(int), stream);
    prep_kernel<<<castBlocks + 3 + 8, blk, 0, stream>>>(
        x, W1, as1, ad1, W2, as2, ad2,
        x_h, w_att1, w_att2, Wstack1, Wstack2, n4x);
    csr_count<<<eb, blk, 0, stream>>>(ei, deg, E0, Etot);
    csr_scan<<<1, 1024, 0, stream>>>(deg, rowptr, cursor, N);
    csr_fill<<<eb, blk, 0, stream>>>(ei, cursor, colidx, E0, Etot);

    // ---- layer 1 ----
    score_kernel<4, 128><<<(N * 4 + 255) / 256, blk, 0, stream>>>(x_h, w_att1, a_s1, a_d1, N);
    gat_agg1<<<nb4, blk, 0, stream>>>(rowptr, colidx, x_h, a_s1, a_d1, agg1, N);
    gemm_stack<512, 4><<<mb, blk, 0, stream>>>(agg1, Wstack1, h1_h, b1, 0.25f, N);

    // ---- layer 2 ----
    score_kernel<2, 64><<<(N * 2 + 255) / 256, blk, 0, stream>>>(h1_h, w_att2, a_s2, a_d2, N);
    gat_agg2<<<nb4, blk, 0, stream>>>(rowptr, colidx, h1_h, a_s2, a_d2, agg2, N);
    gemm_stack<128, 2><<<mb, blk, 0, stream>>>(agg2, Wstack2, h2_h, b2, 0.5f, N);

    // ---- pool + heads ----
    pool_pergraph<<<G_GRAPHS, blk, 0, stream>>>(h2_h, bat, emb, N);
    heads_kernel<<<1, 64, 0, stream>>>(emb, cW1, cb1, cW2, cb2,
                                       hW1, hb1, hW2, hb2, (float*)d_out);
}

// Round 8
// 253.023 us; speedup vs baseline: 1.1056x; 1.1056x over previous
//
#include <hip/hip_runtime.h>
#include <hip/hip_fp16.h>

// ---------------------------------------------------------------------------
// GAT policy module: 2x GAT layer (head-mean) + mean-pool + 2 MLP heads.
// Round 7: revert to R5 structure (R6 dataflow flip regressed: agg
// materialization round-trip cost > gather-table savings). Changes vs R5:
//   - gat_dst gather loop 8-deep (8 loads in flight; was 4) -> more MLP
//   - merged prep kernel (x/W1/W2 casts + deg zeroing), 13 -> 10 launches
// MFMA fragment layouts (HW-verified): A[m=lane&15][k=quad*8+j],
// B[k=quad*8+j][n=lane&15], C/D col=lane&15, row=quad*4+reg.
// ---------------------------------------------------------------------------

#define G_GRAPHS 64

using half8   = __attribute__((ext_vector_type(8))) _Float16;
using half4v  = __attribute__((ext_vector_type(4))) _Float16;
using floatx4 = __attribute__((ext_vector_type(4))) float;

// ---------------------------------------------------------------------------
// Merged prep: cast x, W1, W2 to fp16 (4 elems/thread) + zero deg.
// ---------------------------------------------------------------------------
__global__ __launch_bounds__(256) void prep_kernel(
        const float* __restrict__ x, const float* __restrict__ W1,
        const float* __restrict__ W2, _Float16* __restrict__ x_h,
        _Float16* __restrict__ W1_h, _Float16* __restrict__ W2_h,
        int* __restrict__ deg, int n4x, int n4w1, int n4w2, int n4deg)
{
    const int cb1 = (n4x + 255) >> 8;
    const int cb2 = (n4w1 + 255) >> 8;
    const int cb3 = (n4w2 + 255) >> 8;
    const int bid = blockIdx.x;
    const int tid = threadIdx.x;
    if (bid < cb1) {
        int i = bid * 256 + tid;
        if (i < n4x) {
            float4 v = reinterpret_cast<const float4*>(x)[i];
            half4v h = { (_Float16)v.x, (_Float16)v.y, (_Float16)v.z, (_Float16)v.w };
            reinterpret_cast<half4v*>(x_h)[i] = h;
        }
    } else if (bid < cb1 + cb2) {
        int i = (bid - cb1) * 256 + tid;
        if (i < n4w1) {
            float4 v = reinterpret_cast<const float4*>(W1)[i];
            half4v h = { (_Float16)v.x, (_Float16)v.y, (_Float16)v.z, (_Float16)v.w };
            reinterpret_cast<half4v*>(W1_h)[i] = h;
        }
    } else if (bid < cb1 + cb2 + cb3) {
        int i = (bid - cb1 - cb2) * 256 + tid;
        if (i < n4w2) {
            float4 v = reinterpret_cast<const float4*>(W2)[i];
            half4v h = { (_Float16)v.x, (_Float16)v.y, (_Float16)v.z, (_Float16)v.w };
            reinterpret_cast<half4v*>(W2_h)[i] = h;
        }
    } else {
        int i = (bid - cb1 - cb2 - cb3) * 256 + tid;
        if (i < n4deg) {
            int4 z = make_int4(0, 0, 0, 0);
            reinterpret_cast<int4*>(deg)[i] = z;
        }
    }
}

// ---------------------------------------------------------------------------
// MFMA fp16 GEMM (64x64 tile per block, whole K in LDS) + fused att-coef.
//   Ch[m, col0+*] = A[m,:K] @ B[:K, col0+*]   (fp16 out, fp32 accum)
//   a_s[m, head] = sum_c Ch[m, head-cols c] * att_s[head, c]  (from acc)
// HPB = heads per 64-col block (L1: 1 head x 64ch, L2: 2 heads x 32ch).
// ---------------------------------------------------------------------------
template<int K, int HPB>
__global__ __launch_bounds__(256) void gemm_mfma_att(
        const _Float16* __restrict__ A, const _Float16* __restrict__ B,
        _Float16* __restrict__ Ch, const float* __restrict__ att_s,
        const float* __restrict__ att_d, float* __restrict__ a_s,
        float* __restrict__ a_d, int M, int Ntot, int Htot)
{
    constexpr int CPH = 64 / HPB;        // channels per head
    constexpr int NTH = 4 / HPB;         // col-tiles (of 16) per head
    __shared__ _Float16 As[64][K + 8];   // row-major, +8 pad
    __shared__ _Float16 Bt[64][K + 8];   // transposed: Bt[n][k]

    const int tid  = threadIdx.x;
    const int row0 = blockIdx.x * 64;
    const int col0 = blockIdx.y * 64;

    // ---- stage A tile: 64 rows x K halves ----
    {
        int row = tid >> 2;
        int kc  = (tid & 3) * (K / 4);
        int gr  = row0 + row;
        #pragma unroll
        for (int i = 0; i < K / 32; i++) {
            half8 v = {};
            if (gr < M)
                v = *reinterpret_cast<const half8*>(&A[(size_t)gr * K + kc + i * 8]);
            *reinterpret_cast<half8*>(&As[row][kc + i * 8]) = v;
        }
    }
    // ---- stage B tile transposed: Bt[n][k] ----
    {
        #pragma unroll
        for (int i = 0; i < K / 16; i++) {
            int id = tid + 256 * i;
            int k  = id >> 4;
            int n4 = (id & 15) * 4;
            half4v v = *reinterpret_cast<const half4v*>(&B[(size_t)k * Ntot + col0 + n4]);
            Bt[n4 + 0][k] = v[0]; Bt[n4 + 1][k] = v[1];
            Bt[n4 + 2][k] = v[2]; Bt[n4 + 3][k] = v[3];
        }
    }
    __syncthreads();

    const int wid  = tid >> 6;
    const int lane = tid & 63;
    const int r    = lane & 15;
    const int quad = lane >> 4;
    const int rw0  = wid * 16;           // wave's 16-row slice

    floatx4 acc[4] = {};
    #pragma unroll
    for (int s = 0; s < K / 32; s++) {
        half8 af = *reinterpret_cast<const half8*>(&As[rw0 + r][s * 32 + quad * 8]);
        #pragma unroll
        for (int nt = 0; nt < 4; nt++) {
            half8 bf = *reinterpret_cast<const half8*>(&Bt[nt * 16 + r][s * 32 + quad * 8]);
            acc[nt] = __builtin_amdgcn_mfma_f32_16x16x32_f16(af, bf, acc[nt], 0, 0, 0);
        }
    }

    // ---- store Ch (fp16) ----
    #pragma unroll
    for (int nt = 0; nt < 4; nt++) {
        #pragma unroll
        for (int reg = 0; reg < 4; reg++) {
            int gr = row0 + rw0 + quad * 4 + reg;
            if (gr < M)
                Ch[(size_t)gr * Ntot + col0 + nt * 16 + r] = (_Float16)acc[nt][reg];
        }
    }

    // ---- fused att-coef: per-row dot with att weights, 16-lane reduce ----
    float ps[HPB][4], pd[HPB][4];
    #pragma unroll
    for (int hl = 0; hl < HPB; hl++)
        #pragma unroll
        for (int reg = 0; reg < 4; reg++) { ps[hl][reg] = 0.f; pd[hl][reg] = 0.f; }

    #pragma unroll
    for (int nt = 0; nt < 4; nt++) {
        int hl = nt / NTH;
        int cl = (nt % NTH) * 16 + r;
        int hglob = blockIdx.y * HPB + hl;
        float ws = att_s[hglob * CPH + cl];
        float wd = att_d[hglob * CPH + cl];
        #pragma unroll
        for (int reg = 0; reg < 4; reg++) {
            ps[hl][reg] += acc[nt][reg] * ws;
            pd[hl][reg] += acc[nt][reg] * wd;
        }
    }
    #pragma unroll
    for (int off = 1; off < 16; off <<= 1)
        #pragma unroll
        for (int hl = 0; hl < HPB; hl++)
            #pragma unroll
            for (int reg = 0; reg < 4; reg++) {
                ps[hl][reg] += __shfl_xor(ps[hl][reg], off);
                pd[hl][reg] += __shfl_xor(pd[hl][reg], off);
            }
    if (r == 0) {
        #pragma unroll
        for (int reg = 0; reg < 4; reg++) {
            int gr = row0 + rw0 + quad * 4 + reg;
            if (gr < M) {
                #pragma unroll
                for (int hl = 0; hl < HPB; hl++) {
                    int hglob = blockIdx.y * HPB + hl;
                    a_s[gr * Htot + hglob] = ps[hl][reg];
                    a_d[gr * Htot + hglob] = pd[hl][reg];
                }
            }
        }
    }
}

// ---------------------------------------------------------------------------
// CSR build: degree count -> exclusive scan -> bucket fill.
// ---------------------------------------------------------------------------
__global__ __launch_bounds__(256) void csr_count(
        const int* __restrict__ ei, int* __restrict__ deg, int E0, int Etot)
{
    int idx = blockIdx.x * 256 + threadIdx.x;
    if (idx >= Etot) return;
    int dst = (idx < E0) ? ei[E0 + idx] : (idx - E0);
    atomicAdd(&deg[dst], 1);
}

__global__ __launch_bounds__(1024) void csr_scan(
        const int* __restrict__ deg, int* __restrict__ rowptr,
        int* __restrict__ cursor, int N)
{
    const int tid = threadIdx.x;
    const int items = (N + 1023) >> 10;
    const int b = tid * items;
    int sum = 0;
    for (int k = 0; k < items; k++) {
        int i = b + k;
        sum += (i < N) ? deg[i] : 0;
    }
    __shared__ int smem[1024];
    smem[tid] = sum;
    __syncthreads();
    for (int off = 1; off < 1024; off <<= 1) {
        int t = (tid >= off) ? smem[tid - off] : 0;
        __syncthreads();
        smem[tid] += t;
        __syncthreads();
    }
    int excl = smem[tid] - sum;
    for (int k = 0; k < items; k++) {
        int i = b + k;
        if (i < N) {
            rowptr[i] = excl; cursor[i] = excl;
            excl += deg[i];
        }
    }
    if (tid == 1023) rowptr[N] = excl;
}

__global__ __launch_bounds__(256) void csr_fill(
        const int* __restrict__ ei, int* __restrict__ cursor,
        int* __restrict__ col, int E0, int Etot)
{
    int idx = blockIdx.x * 256 + threadIdx.x;
    if (idx >= Etot) return;
    int src = (idx < E0) ? ei[idx]      : (idx - E0);
    int dst = (idx < E0) ? ei[E0 + idx] : (idx - E0);
    int pos = atomicAdd(&cursor[dst], 1);
    col[pos] = src;
}

// ---------------------------------------------------------------------------
// fp16 FMA helper: 4 halves (as float2 raw) into 4-float acc.
// ---------------------------------------------------------------------------
__device__ inline void facc4(float* a, float2 raw, float p) {
    __half2 h0 = *reinterpret_cast<__half2*>(&raw.x);
    __half2 h1 = *reinterpret_cast<__half2*>(&raw.y);
    float2 f0 = __half22float2(h0), f1 = __half22float2(h1);
    a[0] += p * f0.x; a[1] += p * f0.y; a[2] += p * f1.x; a[3] += p * f1.y;
}

// ---------------------------------------------------------------------------
// Fused GAT aggregation, one wave per dst node. 256 thr = 4 waves/block.
// Gather loop: 8 loads in flight (addresses+weights hoisted). OUT_HALF:
// layer-1 writes fp16 for the layer-2 MFMA GEMM.
// ---------------------------------------------------------------------------
template<int H, int C, bool OUT_HALF>
__global__ __launch_bounds__(256) void gat_dst(
        const int* __restrict__ rowptr, const int* __restrict__ colidx,
        const __half* __restrict__ hfeat, const float* __restrict__ a_s,
        const float* __restrict__ a_d, const float* __restrict__ bias,
        void* __restrict__ out_v, int N)
{
    constexpr int FV = (H * C) / 64;
    const int wid  = threadIdx.x >> 6;
    const int lane = threadIdx.x & 63;
    const int d = blockIdx.x * 4 + wid;

    __shared__ float p_sh[4][64 * H];

    if (d >= N) return;
    const int lo = rowptr[d], hi = rowptr[d + 1];
    const int deg = hi - lo;
    const int h_lane = (lane * FV) / C;

    float adp[H];
    #pragma unroll
    for (int h = 0; h < H; h++) adp[h] = a_d[d * H + h];

    float lh[H];
    #pragma unroll
    for (int h = 0; h < H; h++) lh[h] = 0.f;
    float acc[FV];
    #pragma unroll
    for (int v = 0; v < FV; v++) acc[v] = 0.f;

    if (deg <= 64) {
        int s = 0;
        float e[H];
        const bool valid = lane < deg;
        if (valid) {
            s = colidx[lo + lane];
            if constexpr (H == 4) {
                float4 av = *reinterpret_cast<const float4*>(&a_s[s * 4]);
                float ev[4] = {av.x + adp[0], av.y + adp[1],
                               av.z + adp[2], av.w + adp[3]};
                #pragma unroll
                for (int h = 0; h < 4; h++)
                    e[h] = (ev[h] > 0.f) ? ev[h] : 0.2f * ev[h];
            } else {
                float2 av = *reinterpret_cast<const float2*>(&a_s[s * 2]);
                float ev[2] = {av.x + adp[0], av.y + adp[1]};
                #pragma unroll
                for (int h = 0; h < 2; h++)
                    e[h] = (ev[h] > 0.f) ? ev[h] : 0.2f * ev[h];
            }
        } else {
            #pragma unroll
            for (int h = 0; h < H; h++) e[h] = -3.0e38f;
        }
        float mh[H];
        #pragma unroll
        for (int h = 0; h < H; h++) mh[h] = e[h];
        #pragma unroll
        for (int off = 1; off < 64; off <<= 1)
            #pragma unroll
            for (int h = 0; h < H; h++)
                mh[h] = fmaxf(mh[h], __shfl_xor(mh[h], off));

        if (valid) {
            #pragma unroll
            for (int h = 0; h < H; h++) {
                float p = __expf(e[h] - mh[h]);
                lh[h] = p;
                p_sh[wid][lane * H + h] = p;
            }
        }
        #pragma unroll
        for (int off = 1; off < 64; off <<= 1)
            #pragma unroll
            for (int h = 0; h < H; h++)
                lh[h] += __shfl_xor(lh[h], off);

        // ---- 8-deep gather: 8 loads in flight, 4 accumulator sets ----
        float acc1[FV], acc2[FV], acc3[FV];
        #pragma unroll
        for (int v = 0; v < FV; v++) { acc1[v] = 0.f; acc2[v] = 0.f; acc3[v] = 0.f; }
        float* accs[4] = { acc, acc1, acc2, acc3 };
        int j = 0;
        if constexpr (FV == 4) {
            for (; j + 8 <= deg; j += 8) {
                float2 raw[8]; float pj[8];
                #pragma unroll
                for (int u = 0; u < 8; u++) {
                    int sj = __shfl(s, j + u);
                    pj[u] = p_sh[wid][(j + u) * H + h_lane];
                    raw[u] = *reinterpret_cast<const float2*>(
                        hfeat + (size_t)sj * (H * C) + lane * 4);
                }
                #pragma unroll
                for (int u = 0; u < 8; u++)
                    facc4(accs[u & 3], raw[u], pj[u]);
            }
            for (; j < deg; j++) {
                int sj = __shfl(s, j);
                float pj = p_sh[wid][j * H + h_lane];
                float2 raw = *reinterpret_cast<const float2*>(
                    hfeat + (size_t)sj * (H * C) + lane * 4);
                facc4(acc, raw, pj);
            }
        } else {
            for (; j + 8 <= deg; j += 8) {
                __half raw[8]; float pj[8];
                #pragma unroll
                for (int u = 0; u < 8; u++) {
                    int sj = __shfl(s, j + u);
                    pj[u] = p_sh[wid][(j + u) * H + h_lane];
                    raw[u] = hfeat[(size_t)sj * (H * C) + lane];
                }
                #pragma unroll
                for (int u = 0; u < 8; u++)
                    accs[u & 3][0] += pj[u] * __half2float(raw[u]);
            }
            for (; j < deg; j++) {
                int sj = __shfl(s, j);
                float pj = p_sh[wid][j * H + h_lane];
                acc[0] += pj * __half2float(hfeat[(size_t)sj * (H * C) + lane]);
            }
        }
        #pragma unroll
        for (int v = 0; v < FV; v++)
            acc[v] = (acc[v] + acc1[v]) + (acc2[v] + acc3[v]);
    } else {
        // ---------------- general path (deg > 64, rare) -------------------
        float mh[H];
        #pragma unroll
        for (int h = 0; h < H; h++) mh[h] = -3.0e38f;
        for (int i = lo + lane; i < hi; i += 64) {
            int s = colidx[i];
            #pragma unroll
            for (int h = 0; h < H; h++) {
                float v = a_s[s * H + h] + adp[h];
                v = (v > 0.f) ? v : 0.2f * v;
                mh[h] = fmaxf(mh[h], v);
            }
        }
        #pragma unroll
        for (int off = 1; off < 64; off <<= 1)
            #pragma unroll
            for (int h = 0; h < H; h++)
                mh[h] = fmaxf(mh[h], __shfl_xor(mh[h], off));

        for (int base = lo; base < hi; base += 64) {
            int i = base + lane;
            int s = 0;
            if (i < hi) {
                s = colidx[i];
                #pragma unroll
                for (int h = 0; h < H; h++) {
                    float v = a_s[s * H + h] + adp[h];
                    v = (v > 0.f) ? v : 0.2f * v;
                    float p = __expf(v - mh[h]);
                    lh[h] += p;
                    p_sh[wid][(i - base) * H + h] = p;
                }
            }
            int cnt = min(64, hi - base);
            for (int j = 0; j < cnt; j++) {
                int s_j = __shfl(s, j);
                float pj = p_sh[wid][j * H + h_lane];
                if constexpr (FV == 4) {
                    float2 raw = *reinterpret_cast<const float2*>(
                        hfeat + (size_t)s_j * (H * C) + lane * 4);
                    facc4(acc, raw, pj);
                } else {
                    acc[0] += pj * __half2float(hfeat[(size_t)s_j * (H * C) + lane]);
                }
            }
        }
        #pragma unroll
        for (int off = 1; off < 64; off <<= 1)
            #pragma unroll
            for (int h = 0; h < H; h++)
                lh[h] += __shfl_xor(lh[h], off);
    }

    // ---------------- epilogue ----------------
    float lsel = lh[0];
    #pragma unroll
    for (int h = 1; h < H; h++) if (h_lane == h) lsel = lh[h];
    const float inv = 1.0f / (lsel + 1e-16f);

    if constexpr (FV == 4) {           // H=4, C=64
        float vx = acc[0] * inv, vy = acc[1] * inv,
              vz = acc[2] * inv, vw = acc[3] * inv;
        vx += __shfl_xor(vx, 16); vy += __shfl_xor(vy, 16);
        vz += __shfl_xor(vz, 16); vw += __shfl_xor(vw, 16);
        vx += __shfl_xor(vx, 32); vy += __shfl_xor(vy, 32);
        vz += __shfl_xor(vz, 32); vw += __shfl_xor(vw, 32);
        if (lane < 16) {
            float4 bv = *reinterpret_cast<const float4*>(&bias[lane * 4]);
            float ox = fmaxf(0.25f * vx + bv.x, 0.f);
            float oy = fmaxf(0.25f * vy + bv.y, 0.f);
            float oz = fmaxf(0.25f * vz + bv.z, 0.f);
            float ow = fmaxf(0.25f * vw + bv.w, 0.f);
            if constexpr (OUT_HALF) {
                half4v hv = { (_Float16)ox, (_Float16)oy, (_Float16)oz, (_Float16)ow };
                *reinterpret_cast<half4v*>((_Float16*)out_v + (size_t)d * C + lane * 4) = hv;
            } else {
                float4 o = make_float4(ox, oy, oz, ow);
                *reinterpret_cast<float4*>((float*)out_v + (size_t)d * C + lane * 4) = o;
            }
        }
    } else {                           // H=2, C=32
        float v = acc[0] * inv;
        v += __shfl_xor(v, 32);
        if (lane < 32) {
            float o = fmaxf(0.5f * v + bias[lane], 0.f);
            if constexpr (OUT_HALF)
                ((_Float16*)out_v)[(size_t)d * C + lane] = (_Float16)o;
            else
                ((float*)out_v)[(size_t)d * C + lane] = o;
        }
    }
}

// ---------------------------------------------------------------------------
// Global mean pool, one block per graph (batch sorted -> contiguous segments).
// ---------------------------------------------------------------------------
__global__ __launch_bounds__(256) void pool_pergraph(
        const float* __restrict__ h2, const int* __restrict__ batch,
        float* __restrict__ emb, int N)
{
    const int g = blockIdx.x;
    const int c = threadIdx.x & 31;
    const int r = threadIdx.x >> 5;

    __shared__ int bounds[2];
    if (threadIdx.x < 2) {
        int target = g + (int)threadIdx.x;
        int lo = 0, hi = N;
        while (lo < hi) {
            int mid = (lo + hi) >> 1;
            if (batch[mid] < target) lo = mid + 1; else hi = mid;
        }
        bounds[threadIdx.x] = lo;
    }
    __syncthreads();
    const int lo = bounds[0], hi = bounds[1];

    float acc = 0.f;
    for (int n = lo + r; n < hi; n += 8)
        acc += h2[(size_t)n * 32 + c];

    __shared__ float red[8][32];
    red[r][c] = acc;
    __syncthreads();
    if (r == 0) {
        float s = 0.f;
        #pragma unroll
        for (int i = 0; i < 8; i++) s += red[i][c];
        emb[g * 32 + c] = s / fmaxf((float)(hi - lo), 1.0f);
    }
}

// ---------------------------------------------------------------------------
// Heads: two 32->16->1 MLPs + sigmoid. out[0:64]=halt, out[64:128]=cont.
// ---------------------------------------------------------------------------
__global__ __launch_bounds__(64) void heads_kernel(
        const float* __restrict__ embg,
        const float* __restrict__ cW1, const float* __restrict__ cb1,
        const float* __restrict__ cW2, const float* __restrict__ cb2,
        const float* __restrict__ hW1, const float* __restrict__ hb1,
        const float* __restrict__ hW2, const float* __restrict__ hb2,
        float* __restrict__ out)
{
    int g = threadIdx.x;
    if (g >= G_GRAPHS) return;
    float emb[32];
    #pragma unroll
    for (int c = 0; c < 32; c++) emb[c] = embg[g * 32 + c];

    float sc = cb2[0];
    #pragma unroll
    for (int j = 0; j < 16; j++) {
        float s = cb1[j];
        #pragma unroll
        for (int c = 0; c < 32; c++) s += emb[c] * cW1[c * 16 + j];
        sc += fmaxf(s, 0.f) * cW2[j];
    }
    float cont = 1.0f / (1.0f + __expf(-sc));

    float sh = hb2[0];
    #pragma unroll
    for (int j = 0; j < 16; j++) {
        float s = hb1[j];
        #pragma unroll
        for (int c = 0; c < 32; c++) s += emb[c] * hW1[c * 16 + j];
        sh += fmaxf(s, 0.f) * hW2[j];
    }
    float halt = 1.0f / (1.0f + __expf(-sh));

    out[g] = halt;
    out[G_GRAPHS + g] = cont;
}

// ---------------------------------------------------------------------------
extern "C" void kernel_launch(void* const* d_in, const int* in_sizes, int n_in,
                              void* d_out, int out_size, void* d_ws, size_t ws_size,
                              hipStream_t stream)
{
    const float* x   = (const float*)d_in[0];
    const int*   ei  = (const int*)  d_in[1];
    const int*   bat = (const int*)  d_in[2];
    const float* W1  = (const float*)d_in[3];
    const float* as1 = (const float*)d_in[4];
    const float* ad1 = (const float*)d_in[5];
    const float* b1  = (const float*)d_in[6];
    const float* W2  = (const float*)d_in[7];
    const float* as2 = (const float*)d_in[8];
    const float* ad2 = (const float*)d_in[9];
    const float* b2  = (const float*)d_in[10];
    const float* cW1 = (const float*)d_in[11];
    const float* cb1 = (const float*)d_in[12];
    const float* cW2 = (const float*)d_in[13];
    const float* cb2 = (const float*)d_in[14];
    const float* hW1 = (const float*)d_in[15];
    const float* hb1 = (const float*)d_in[16];
    const float* hW2 = (const float*)d_in[17];
    const float* hb2 = (const float*)d_in[18];

    const int N    = in_sizes[2];           // 20000
    const int E0   = in_sizes[1] / 2;       // 320000
    const int Etot = E0 + N;                // + self loops
    const int IN   = in_sizes[0] / N;       // 128

    // ---- workspace carve (float-granular) ----
    float* w = (float*)d_ws;
    size_t o = 0;
    _Float16* x_h     = (_Float16*)(w + o); o += (size_t)N * IN / 2;   // [N,128]
    _Float16* W1_h    = (_Float16*)(w + o); o += (size_t)IN * 256 / 2; // [128,256]
    _Float16* W2_h    = (_Float16*)(w + o); o += (size_t)64 * 64 / 2;  // [64,64]
    _Float16* h1pre_h = (_Float16*)(w + o); o += (size_t)N * 128;      // [N,256]
    _Float16* h1_h    = (_Float16*)(w + o); o += (size_t)N * 32;       // [N,64]
    _Float16* h2pre_h = (_Float16*)(w + o); o += (size_t)N * 32;       // [N,64]
    float* a_s1  = w + o; o += (size_t)N * 4;
    float* a_d1  = w + o; o += (size_t)N * 4;
    float* a_s2  = w + o; o += (size_t)N * 2;
    float* a_d2  = w + o; o += (size_t)N * 2;
    float* h2    = w + o; o += (size_t)N * 32;
    float* emb   = w + o; o += (size_t)G_GRAPHS * 32;
    int* rowptr  = (int*)(w + o); o += (size_t)N + 1;
    int* cursor  = (int*)(w + o); o += (size_t)N;
    int* deg     = (int*)(w + o); o += (size_t)N;
    int* colidx  = (int*)(w + o); o += (size_t)Etot;
    (void)ws_size; (void)n_in; (void)out_size;

    const dim3 blk(256);
    const int eb  = (Etot + 255) / 256;
    const int nb4 = (N + 3) / 4;
    const int mb  = (N + 63) / 64;

    // ---- merged prep (casts + deg zero) + CSR build ----
    const int n4x  = N * IN / 4;
    const int n4w1 = IN * 256 / 4;
    const int n4w2 = 64 * 64 / 4;
    const int n4d  = N / 4;
    const int prepBlocks = (n4x + 255) / 256 + (n4w1 + 255) / 256
                         + (n4w2 + 255) / 256 + (n4d + 255) / 256;
    prep_kernel<<<prepBlocks, blk, 0, stream>>>(
        x, W1, W2, x_h, W1_h, W2_h, deg, n4x, n4w1, n4w2, n4d);
    csr_count<<<eb, blk, 0, stream>>>(ei, deg, E0, Etot);
    csr_scan<<<1, 1024, 0, stream>>>(deg, rowptr, cursor, N);
    csr_fill<<<eb, blk, 0, stream>>>(ei, cursor, colidx, E0, Etot);

    // ---- layer 1: GAT(128 -> 4 heads x 64, head-mean) + relu ----
    gemm_mfma_att<128, 1><<<dim3(mb, 4), blk, 0, stream>>>(
        x_h, W1_h, h1pre_h, as1, ad1, a_s1, a_d1, N, 256, 4);
    gat_dst<4, 64, true><<<nb4, blk, 0, stream>>>(
        rowptr, colidx, (const __half*)h1pre_h, a_s1, a_d1, b1, h1_h, N);

    // ---- layer 2: GAT(64 -> 2 heads x 32, head-mean) + relu ----
    gemm_mfma_att<64, 2><<<dim3(mb, 1), blk, 0, stream>>>(
        h1_h, W2_h, h2pre_h, as2, ad2, a_s2, a_d2, N, 64, 2);
    gat_dst<2, 32, false><<<nb4, blk, 0, stream>>>(
        rowptr, colidx, (const __half*)h2pre_h, a_s2, a_d2, b2, h2, N);

    // ---- pool + heads (no atomics: batch is sorted) ----
    pool_pergraph<<<G_GRAPHS, blk, 0, stream>>>(h2, bat, emb, N);
    heads_kernel<<<1, 64, 0, stream>>>(emb, cW1, cb1, cW2, cb2,
                                       hW1, hb1, hW2, hb2, (float*)d_out);
}